// Round 1
// baseline (142.566 us; speedup 1.0000x reference)
//
#include <hip/hip_runtime.h>
#include <hip/hip_bf16.h>

#define BATCH 1024
#define INPUT_DIM 1024
#define NBK 32
#define KDIM 16

// ---------------------------------------------------------------------------
// Kernel 1: act2[k][b][m] = sum_d x[b][d] * W[k][d][m]
// M=1024 (b), N=512 (j=k*16+m), K=1024 (d)
// Tile: BM=32, BN=64, BK=32. 512 threads, 2x2 micro-tile.
// A staged transposed in LDS (pad to 36 to spread store banks); compute reads
// of A are wave-broadcast (only 2 distinct addrs/wave).
// ---------------------------------------------------------------------------
__global__ __launch_bounds__(512) void gemm_act(const float* __restrict__ x,
                                                const float* __restrict__ W,
                                                float* __restrict__ act2) {
    __shared__ float xs[32][36];   // [d_local][b_local]
    __shared__ float wsm[32][64];  // [d_local][j_local]
    const int tid = threadIdx.x;
    const int j0 = blockIdx.x * 64;
    const int b0 = blockIdx.y * 32;
    const int tn = tid & 31;       // j group 0..31
    const int tm = tid >> 5;       // b group 0..15
    const int xr = tid >> 4;       // 0..31  (b row for x staging)
    const int xc = tid & 15;       // 0..15  (d pair)
    const int wj = (tid & 15) * 4; // 0..60  (j offset for W staging)
    const int wd = tid >> 4;       // 0..31  (d row for W staging)
    const int kw = (j0 + wj) >> 4;
    const int mw = (j0 + wj) & 15;

    float acc00 = 0.f, acc01 = 0.f, acc10 = 0.f, acc11 = 0.f;

    for (int d0 = 0; d0 < INPUT_DIM; d0 += 32) {
        float2 xv = *(const float2*)&x[(b0 + xr) * INPUT_DIM + d0 + xc * 2];
        float4 wv = *(const float4*)&W[kw * (INPUT_DIM * KDIM) + (d0 + wd) * KDIM + mw];
        __syncthreads();
        xs[xc * 2 + 0][xr] = xv.x;
        xs[xc * 2 + 1][xr] = xv.y;
        *(float4*)&wsm[wd][wj] = wv;
        __syncthreads();
#pragma unroll
        for (int kk = 0; kk < 32; kk++) {
            float2 a  = *(const float2*)&xs[kk][tm * 2];
            float2 bv = *(const float2*)&wsm[kk][tn * 2];
            acc00 += a.x * bv.x;
            acc01 += a.x * bv.y;
            acc10 += a.y * bv.x;
            acc11 += a.y * bv.y;
        }
    }

    const int j = j0 + tn * 2;     // j and j+1 are in the same k (j even)
    const int k = j >> 4;
    const int m = j & 15;
    const int b = b0 + tm * 2;
    *(float2*)&act2[k * (BATCH * KDIM) + b * KDIM + m]       = make_float2(acc00, acc01);
    *(float2*)&act2[k * (BATCH * KDIM) + (b + 1) * KDIM + m] = make_float2(acc10, acc11);
}

// ---------------------------------------------------------------------------
// Kernel 2: partial minibatch features.
// grid = (c_chunk=8, b_tile=4, k=32); block = 256 threads, 1 b per thread.
// Each block: stage 128 c-rows (8 KB) in LDS, thread's own b-row in 16 VGPRs.
// All lanes read the same c-row -> LDS broadcast, conflict-free.
// part[chunk][k][b] = sum_{c in chunk} exp(-L1(act[b,k,:], act[c,k,:]))
// ---------------------------------------------------------------------------
__global__ __launch_bounds__(256) void pairwise(const float* __restrict__ act2,
                                                float* __restrict__ part) {
    __shared__ float cs[128 * KDIM];  // 8 KB
    const int tid = threadIdx.x;
    const int k  = blockIdx.z;
    const int b  = blockIdx.y * 256 + tid;
    const int c0 = blockIdx.x * 128;
    const float* base = act2 + k * (BATCH * KDIM);

    // stage c-chunk (contiguous 8 KB, fully coalesced)
    const float4* src = (const float4*)(base + c0 * KDIM);
    float4* dst = (float4*)cs;
    dst[tid]       = src[tid];
    dst[tid + 256] = src[tid + 256];

    // own row: 4x float4, 16 B/lane, coalesced
    float a[16];
#pragma unroll
    for (int i = 0; i < 4; i++) {
        float4 v = *(const float4*)(base + b * KDIM + i * 4);
        a[i * 4 + 0] = v.x; a[i * 4 + 1] = v.y;
        a[i * 4 + 2] = v.z; a[i * 4 + 3] = v.w;
    }
    __syncthreads();

    float feat = 0.f;
    for (int c = 0; c < 128; c++) {
        const float4 r0 = *(const float4*)&cs[c * 16 + 0];
        const float4 r1 = *(const float4*)&cs[c * 16 + 4];
        const float4 r2 = *(const float4*)&cs[c * 16 + 8];
        const float4 r3 = *(const float4*)&cs[c * 16 + 12];
        float s0 = fabsf(a[0]  - r0.x) + fabsf(a[1]  - r0.y)
                 + fabsf(a[2]  - r0.z) + fabsf(a[3]  - r0.w);
        float s1 = fabsf(a[4]  - r1.x) + fabsf(a[5]  - r1.y)
                 + fabsf(a[6]  - r1.z) + fabsf(a[7]  - r1.w);
        float s2 = fabsf(a[8]  - r2.x) + fabsf(a[9]  - r2.y)
                 + fabsf(a[10] - r2.z) + fabsf(a[11] - r2.w);
        float s3 = fabsf(a[12] - r3.x) + fabsf(a[13] - r3.y)
                 + fabsf(a[14] - r3.z) + fabsf(a[15] - r3.w);
        float s = (s0 + s1) + (s2 + s3);
        feat += __expf(-s);
    }
    part[blockIdx.x * (NBK * BATCH) + k * BATCH + b] = feat;
}

// ---------------------------------------------------------------------------
// Kernel 3: out[b][0:1024] = x[b][:]; out[b][1024+k] = sum_{chunks} part
// ---------------------------------------------------------------------------
__global__ __launch_bounds__(256) void combine(const float* __restrict__ x,
                                               const float* __restrict__ part,
                                               float* __restrict__ out) {
    const int t = blockIdx.x * 256 + threadIdx.x;  // < 1024*1056 exactly
    const int b = t / 1056;
    const int j = t - b * 1056;
    if (j < 1024) {
        out[t] = x[b * 1024 + j];
    } else {
        const int k = j - 1024;
        float s = 0.f;
#pragma unroll
        for (int i = 0; i < 8; i++) s += part[i * (NBK * BATCH) + k * BATCH + b];
        out[t] = s;
    }
}

extern "C" void kernel_launch(void* const* d_in, const int* in_sizes, int n_in,
                              void* d_out, int out_size, void* d_ws, size_t ws_size,
                              hipStream_t stream) {
    const float* x = (const float*)d_in[0];
    const float* W = (const float*)d_in[1];
    float* out  = (float*)d_out;
    float* act2 = (float*)d_ws;                  // 32*1024*16 floats = 2 MB
    float* part = act2 + NBK * BATCH * KDIM;     // 8*32*1024 floats  = 1 MB

    gemm_act<<<dim3(8, 32), 512, 0, stream>>>(x, W, act2);
    pairwise<<<dim3(8, 4, 32), 256, 0, stream>>>(act2, part);
    combine<<<(BATCH * 1056) / 256, 256, 0, stream>>>(x, part, out);
}

// Round 2
// 114.382 us; speedup vs baseline: 1.2464x; 1.2464x over previous
//
#include <hip/hip_runtime.h>
#include <hip/hip_bf16.h>

#define BATCH 1024
#define INPUT_DIM 1024
#define NBK 32
#define KDIM 16

typedef __attribute__((ext_vector_type(8))) short short8;
typedef __attribute__((ext_vector_type(8))) unsigned short ushort8;
typedef __attribute__((ext_vector_type(4))) float f32x4;

static __device__ __forceinline__ unsigned short f2bf(float f) {
    union { float f; unsigned u; } v; v.f = f;
    unsigned r = v.u + 0x7fffu + ((v.u >> 16) & 1u);   // RNE
    return (unsigned short)(r >> 16);
}

// ---------------------------------------------------------------------------
// Kernel 0: x (fp32, 1M) -> xb (bf16). 6 MB traffic, memory-bound ~1 us.
// ---------------------------------------------------------------------------
__global__ __launch_bounds__(256) void convert_x(const float* __restrict__ x,
                                                 unsigned short* __restrict__ xb) {
    const int i = (blockIdx.x * 256 + threadIdx.x) * 8;
    float4 v0 = *(const float4*)(x + i);
    float4 v1 = *(const float4*)(x + i + 4);
    ushort8 o;
    o[0] = f2bf(v0.x); o[1] = f2bf(v0.y); o[2] = f2bf(v0.z); o[3] = f2bf(v0.w);
    o[4] = f2bf(v1.x); o[5] = f2bf(v1.y); o[6] = f2bf(v1.z); o[7] = f2bf(v1.w);
    *(ushort8*)(xb + i) = o;
}

// ---------------------------------------------------------------------------
// Kernel 1: act2[k][b][m] = sum_d x[b][d]*W[k][d][m]  via bf16 MFMA 16x16x32.
// Block: 256 thr (4 waves), 1 k-slice, 128 b-rows, K-loop 32 slabs of 32 d.
// A-frag: lane holds x[b0+bsub+(lane&15)][d0 + (lane>>4)*8 + j]  (m89/m91).
// B-frag: lane holds W[k][d0+(lane>>4)*8+j][lane&15] -> staged transposed
//         in LDS wt[m][d] (fp32 read + cvt at stage time; W read once per k).
// C/D: col=lane&15, row=(lane>>4)*4+reg.
// Software pipeline: next slab's global loads in regs before compute.
// ---------------------------------------------------------------------------
#define XPAD 40   // bf16 elements per LDS row (80 B: bank-spread, 16B-aligned)

__global__ __launch_bounds__(256) void gemm_mfma(const unsigned short* __restrict__ xb,
                                                 const float* __restrict__ W,
                                                 float* __restrict__ act2) {
    __shared__ unsigned short xs[128 * XPAD];  // 10 KB
    __shared__ unsigned short wt[16 * XPAD];   // 1.25 KB
    const int tid  = threadIdx.x;
    const int b0   = blockIdx.x * 128;
    const int k    = blockIdx.y;
    const int lane = tid & 63;
    const int wv   = tid >> 6;
    const int quad = lane >> 4;
    const int m16  = lane & 15;

    // x staging: thread covers rows (srow, srow+64), 8 bf16 each at d-offset sch*8
    const int srow = tid >> 2;       // 0..63
    const int sch  = tid & 3;        // 0..3
    const unsigned short* xsrc0 = xb + (b0 + srow) * INPUT_DIM + sch * 8;
    const unsigned short* xsrc1 = xb + (b0 + srow + 64) * INPUT_DIM + sch * 8;
    // W staging (threads 0..127): dd = d-local 0..31, mm = m-group*4
    const int dd = tid >> 2;
    const int mm = (tid & 3) * 4;
    const float* wsrc = W + k * (INPUT_DIM * KDIM) + dd * KDIM + mm;

    f32x4 acc0 = {0.f, 0.f, 0.f, 0.f};
    f32x4 acc1 = {0.f, 0.f, 0.f, 0.f};

    uint4 xr0 = *(const uint4*)(xsrc0);
    uint4 xr1 = *(const uint4*)(xsrc1);
    float4 wr;
    if (tid < 128) wr = *(const float4*)(wsrc);

    for (int s = 0; s < 32; ++s) {
        __syncthreads();
        *(uint4*)&xs[srow * XPAD + sch * 8]        = xr0;
        *(uint4*)&xs[(srow + 64) * XPAD + sch * 8] = xr1;
        if (tid < 128) {
            wt[(mm + 0) * XPAD + dd] = f2bf(wr.x);
            wt[(mm + 1) * XPAD + dd] = f2bf(wr.y);
            wt[(mm + 2) * XPAD + dd] = f2bf(wr.z);
            wt[(mm + 3) * XPAD + dd] = f2bf(wr.w);
        }
        __syncthreads();
        if (s < 31) {
            xr0 = *(const uint4*)(xsrc0 + (s + 1) * 32);
            xr1 = *(const uint4*)(xsrc1 + (s + 1) * 32);
            if (tid < 128) wr = *(const float4*)(wsrc + (s + 1) * 32 * KDIM);
        }
        short8 bf = *(const short8*)&wt[m16 * XPAD + quad * 8];
        short8 a0 = *(const short8*)&xs[(wv * 32 + m16) * XPAD + quad * 8];
        short8 a1 = *(const short8*)&xs[(wv * 32 + 16 + m16) * XPAD + quad * 8];
        acc0 = __builtin_amdgcn_mfma_f32_16x16x32_bf16(a0, bf, acc0, 0, 0, 0);
        acc1 = __builtin_amdgcn_mfma_f32_16x16x32_bf16(a1, bf, acc1, 0, 0, 0);
    }

    const int row0 = b0 + wv * 32 + quad * 4;
#pragma unroll
    for (int r = 0; r < 4; ++r) {
        act2[(k * BATCH + row0 + r) * KDIM + m16]      = acc0[r];
        act2[(k * BATCH + row0 + 16 + r) * KDIM + m16] = acc1[r];
    }
}

// ---------------------------------------------------------------------------
// Kernel 2: partial minibatch features, 4 b-rows per thread.
// grid = (c_chunk=16, k=32) = 512 blocks x 256 thr. LDS: 64 c-rows (4 KB),
// broadcast reads (conflict-free). Register double-buffer of c-row.
// part[chunk][k][b] = sum_{c in chunk} exp(-L1(act[b,k,:], act[c,k,:]))
// ---------------------------------------------------------------------------
__global__ __launch_bounds__(256) void pairwise(const float* __restrict__ act2,
                                                float* __restrict__ part) {
    __shared__ float cs[64 * KDIM];  // 4 KB
    const int tid = threadIdx.x;
    const int k   = blockIdx.y;
    const int c0  = blockIdx.x * 64;
    const float* base = act2 + k * (BATCH * KDIM);

    ((float4*)cs)[tid] = ((const float4*)(base + c0 * KDIM))[tid];

    float a[4][16];
#pragma unroll
    for (int r = 0; r < 4; ++r) {
#pragma unroll
        for (int i = 0; i < 4; ++i) {
            float4 v = *(const float4*)(base + (tid + r * 256) * KDIM + i * 4);
            a[r][i * 4 + 0] = v.x; a[r][i * 4 + 1] = v.y;
            a[r][i * 4 + 2] = v.z; a[r][i * 4 + 3] = v.w;
        }
    }
    __syncthreads();

    float f0 = 0.f, f1 = 0.f, f2 = 0.f, f3 = 0.f;
    float4 r0 = *(const float4*)&cs[0];
    float4 r1 = *(const float4*)&cs[4];
    float4 r2 = *(const float4*)&cs[8];
    float4 r3 = *(const float4*)&cs[12];
    for (int c = 0; c < 64; ++c) {
        float4 n0, n1, n2, n3;
        if (c < 63) {
            n0 = *(const float4*)&cs[(c + 1) * 16 + 0];
            n1 = *(const float4*)&cs[(c + 1) * 16 + 4];
            n2 = *(const float4*)&cs[(c + 1) * 16 + 8];
            n3 = *(const float4*)&cs[(c + 1) * 16 + 12];
        }
#define ROWSUM(rr)                                                           \
        (fabsf(a[rr][0]  - r0.x) + fabsf(a[rr][1]  - r0.y) +                 \
         fabsf(a[rr][2]  - r0.z) + fabsf(a[rr][3]  - r0.w) +                 \
         fabsf(a[rr][4]  - r1.x) + fabsf(a[rr][5]  - r1.y) +                 \
         fabsf(a[rr][6]  - r1.z) + fabsf(a[rr][7]  - r1.w) +                 \
         fabsf(a[rr][8]  - r2.x) + fabsf(a[rr][9]  - r2.y) +                 \
         fabsf(a[rr][10] - r2.z) + fabsf(a[rr][11] - r2.w) +                 \
         fabsf(a[rr][12] - r3.x) + fabsf(a[rr][13] - r3.y) +                 \
         fabsf(a[rr][14] - r3.z) + fabsf(a[rr][15] - r3.w))
        f0 += __expf(-ROWSUM(0));
        f1 += __expf(-ROWSUM(1));
        f2 += __expf(-ROWSUM(2));
        f3 += __expf(-ROWSUM(3));
#undef ROWSUM
        r0 = n0; r1 = n1; r2 = n2; r3 = n3;
    }
    float* p = part + blockIdx.x * (NBK * BATCH) + k * BATCH + tid;
    p[0]   = f0;
    p[256] = f1;
    p[512] = f2;
    p[768] = f3;
}

// ---------------------------------------------------------------------------
// Kernel 3: out[b][0:1024] = x; out[b][1024+k] = sum over 16 chunks of part
// ---------------------------------------------------------------------------
__global__ __launch_bounds__(256) void combine(const float* __restrict__ x,
                                               const float* __restrict__ part,
                                               float* __restrict__ out) {
    const int t = blockIdx.x * 256 + threadIdx.x;
    const int b = t / 1056;
    const int j = t - b * 1056;
    if (j < 1024) {
        out[t] = x[b * 1024 + j];
    } else {
        const int k = j - 1024;
        float s = 0.f;
#pragma unroll
        for (int i = 0; i < 16; ++i) s += part[i * (NBK * BATCH) + k * BATCH + b];
        out[t] = s;
    }
}

extern "C" void kernel_launch(void* const* d_in, const int* in_sizes, int n_in,
                              void* d_out, int out_size, void* d_ws, size_t ws_size,
                              hipStream_t stream) {
    const float* x = (const float*)d_in[0];
    const float* W = (const float*)d_in[1];
    float* out = (float*)d_out;

    unsigned short* xb = (unsigned short*)d_ws;                       // 2 MB
    float* act2 = (float*)((char*)d_ws + 2 * 1024 * 1024);            // 2 MB
    float* part = (float*)((char*)d_ws + 4 * 1024 * 1024);            // 2 MB

    convert_x<<<512, 256, 0, stream>>>(x, xb);
    gemm_mfma<<<dim3(8, 32), 256, 0, stream>>>(xb, W, act2);
    pairwise<<<dim3(16, 32), 256, 0, stream>>>(act2, part);
    combine<<<(BATCH * 1056 + 255) / 256, 256, 0, stream>>>(x, part, out);
}

// Round 3
// 109.496 us; speedup vs baseline: 1.3020x; 1.0446x over previous
//
#include <hip/hip_runtime.h>
#include <hip/hip_bf16.h>

#define BATCH 1024
#define INPUT_DIM 1024
#define NBK 32
#define KDIM 16

typedef __attribute__((ext_vector_type(8))) short short8;
typedef __attribute__((ext_vector_type(8))) unsigned short ushort8;
typedef __attribute__((ext_vector_type(4))) float f32x4;

static __device__ __forceinline__ unsigned short f2bf(float f) {
    union { float f; unsigned u; } v; v.f = f;
    unsigned r = v.u + 0x7fffu + ((v.u >> 16) & 1u);   // RNE
    return (unsigned short)(r >> 16);
}

// ---------------------------------------------------------------------------
// Kernel 0 (prep): blocks [0,512): x fp32 -> xb bf16 (row-major b x d).
//                  blocks [512,640): W[k][d][m] fp32 -> Wt[k][m][d] bf16.
// Branch is block-uniform; both sides memory-bound, ~2 us total.
// ---------------------------------------------------------------------------
__global__ __launch_bounds__(256) void prep(const float* __restrict__ x,
                                            const float* __restrict__ W,
                                            unsigned short* __restrict__ xb,
                                            unsigned short* __restrict__ wt) {
    const int blk = blockIdx.x;
    if (blk < 512) {
        const int i = (blk * 256 + threadIdx.x) * 8;
        float4 v0 = *(const float4*)(x + i);
        float4 v1 = *(const float4*)(x + i + 4);
        ushort8 o;
        o[0] = f2bf(v0.x); o[1] = f2bf(v0.y); o[2] = f2bf(v0.z); o[3] = f2bf(v0.w);
        o[4] = f2bf(v1.x); o[5] = f2bf(v1.y); o[6] = f2bf(v1.z); o[7] = f2bf(v1.w);
        *(ushort8*)(xb + i) = o;
    } else {
        const int b2 = blk - 512;                  // 0..127
        const int k  = b2 >> 2;                    // 0..31
        const int d  = (b2 & 3) * 256 + threadIdx.x;
        const float* src = W + (k * INPUT_DIM + d) * KDIM;  // 16 contiguous floats
        float4 v0 = *(const float4*)(src + 0);
        float4 v1 = *(const float4*)(src + 4);
        float4 v2 = *(const float4*)(src + 8);
        float4 v3 = *(const float4*)(src + 12);
        unsigned short* dst = wt + k * (KDIM * INPUT_DIM) + d;  // stride 1024 per m
        dst[0 * INPUT_DIM]  = f2bf(v0.x); dst[1 * INPUT_DIM]  = f2bf(v0.y);
        dst[2 * INPUT_DIM]  = f2bf(v0.z); dst[3 * INPUT_DIM]  = f2bf(v0.w);
        dst[4 * INPUT_DIM]  = f2bf(v1.x); dst[5 * INPUT_DIM]  = f2bf(v1.y);
        dst[6 * INPUT_DIM]  = f2bf(v1.z); dst[7 * INPUT_DIM]  = f2bf(v1.w);
        dst[8 * INPUT_DIM]  = f2bf(v2.x); dst[9 * INPUT_DIM]  = f2bf(v2.y);
        dst[10 * INPUT_DIM] = f2bf(v2.z); dst[11 * INPUT_DIM] = f2bf(v2.w);
        dst[12 * INPUT_DIM] = f2bf(v3.x); dst[13 * INPUT_DIM] = f2bf(v3.y);
        dst[14 * INPUT_DIM] = f2bf(v3.z); dst[15 * INPUT_DIM] = f2bf(v3.w);
    }
}

// ---------------------------------------------------------------------------
// Kernel 1: act2[k][b][m] via bf16 MFMA 16x16x32, DIRECT from L2 (no LDS,
// no barriers). Per wave: 1 k, 32 b-rows (2 A-frags), K-loop 32 slabs of 32 d.
// A lane: xb[(b0 + (lane&15))*1024 + d0 + (lane>>4)*8]   (validated layout)
// B lane: Wt[k][(lane&15)*1024 + d0 + (lane>>4)*8]       (validated layout)
// Grid 512 blocks x 128 thr = 1024 waves = 4 waves/CU; prefetch depth 1.
// ---------------------------------------------------------------------------
__global__ __launch_bounds__(128) void gemm_direct(const unsigned short* __restrict__ xb,
                                                   const unsigned short* __restrict__ wt,
                                                   float* __restrict__ act2) {
    const int tid  = threadIdx.x;
    const int lane = tid & 63;
    const int w    = tid >> 6;                    // 0..1
    const int k    = blockIdx.y;
    const int b0   = blockIdx.x * 64 + w * 32;
    const int m16  = lane & 15;
    const int quad = lane >> 4;

    const unsigned short* a0p = xb + (b0 + m16) * INPUT_DIM + quad * 8;
    const unsigned short* a1p = a0p + 16 * INPUT_DIM;
    const unsigned short* bp  = wt + k * (KDIM * INPUT_DIM) + m16 * INPUT_DIM + quad * 8;

    f32x4 acc0 = {0.f, 0.f, 0.f, 0.f};
    f32x4 acc1 = {0.f, 0.f, 0.f, 0.f};

    short8 A0 = *(const short8*)a0p;
    short8 A1 = *(const short8*)a1p;
    short8 BV = *(const short8*)bp;

#pragma unroll 4
    for (int s = 0; s < 32; ++s) {
        const int sp = (s < 31) ? (s + 1) * 32 : 0;   // wrap: dead value, in-bounds
        short8 nA0 = *(const short8*)(a0p + sp);
        short8 nA1 = *(const short8*)(a1p + sp);
        short8 nBV = *(const short8*)(bp + sp);
        acc0 = __builtin_amdgcn_mfma_f32_16x16x32_bf16(A0, BV, acc0, 0, 0, 0);
        acc1 = __builtin_amdgcn_mfma_f32_16x16x32_bf16(A1, BV, acc1, 0, 0, 0);
        A0 = nA0; A1 = nA1; BV = nBV;
    }

    const int row0 = b0 + quad * 4;                   // C/D: col=lane&15, row=quad*4+r
#pragma unroll
    for (int r = 0; r < 4; ++r) {
        act2[(k * BATCH + row0 + r) * KDIM + m16]      = acc0[r];
        act2[(k * BATCH + row0 + 16 + r) * KDIM + m16] = acc1[r];
    }
}

// ---------------------------------------------------------------------------
// Kernel 2: partial minibatch features, 4 b-rows per thread.
// grid = (c_chunk=16, k=32) = 512 blocks x 256 thr (8 waves/CU).
// LDS: 64 c-rows (4 KB); all lanes read same address -> broadcast, free.
// ---------------------------------------------------------------------------
__global__ __launch_bounds__(256) void pairwise(const float* __restrict__ act2,
                                                float* __restrict__ part) {
    __shared__ float cs[64 * KDIM];  // 4 KB
    const int tid = threadIdx.x;
    const int k   = blockIdx.y;
    const int c0  = blockIdx.x * 64;
    const float* base = act2 + k * (BATCH * KDIM);

    ((float4*)cs)[tid] = ((const float4*)(base + c0 * KDIM))[tid];

    float a[4][16];
#pragma unroll
    for (int r = 0; r < 4; ++r) {
#pragma unroll
        for (int i = 0; i < 4; ++i) {
            float4 v = *(const float4*)(base + (tid + r * 256) * KDIM + i * 4);
            a[r][i * 4 + 0] = v.x; a[r][i * 4 + 1] = v.y;
            a[r][i * 4 + 2] = v.z; a[r][i * 4 + 3] = v.w;
        }
    }
    __syncthreads();

    float f0 = 0.f, f1 = 0.f, f2 = 0.f, f3 = 0.f;
#pragma unroll 2
    for (int c = 0; c < 64; ++c) {
        const float4 r0 = *(const float4*)&cs[c * 16 + 0];
        const float4 r1 = *(const float4*)&cs[c * 16 + 4];
        const float4 r2 = *(const float4*)&cs[c * 16 + 8];
        const float4 r3 = *(const float4*)&cs[c * 16 + 12];
#define ROWSUM(rr)                                                           \
        (fabsf(a[rr][0]  - r0.x) + fabsf(a[rr][1]  - r0.y) +                 \
         fabsf(a[rr][2]  - r0.z) + fabsf(a[rr][3]  - r0.w) +                 \
         fabsf(a[rr][4]  - r1.x) + fabsf(a[rr][5]  - r1.y) +                 \
         fabsf(a[rr][6]  - r1.z) + fabsf(a[rr][7]  - r1.w) +                 \
         fabsf(a[rr][8]  - r2.x) + fabsf(a[rr][9]  - r2.y) +                 \
         fabsf(a[rr][10] - r2.z) + fabsf(a[rr][11] - r2.w) +                 \
         fabsf(a[rr][12] - r3.x) + fabsf(a[rr][13] - r3.y) +                 \
         fabsf(a[rr][14] - r3.z) + fabsf(a[rr][15] - r3.w))
        f0 += __expf(-ROWSUM(0));
        f1 += __expf(-ROWSUM(1));
        f2 += __expf(-ROWSUM(2));
        f3 += __expf(-ROWSUM(3));
#undef ROWSUM
    }
    float* p = part + blockIdx.x * (NBK * BATCH) + k * BATCH + tid;
    p[0]   = f0;
    p[256] = f1;
    p[512] = f2;
    p[768] = f3;
}

// ---------------------------------------------------------------------------
// Kernel 3: out[b][0:1024] = x; out[b][1024+k] = sum over 16 chunks of part
// ---------------------------------------------------------------------------
__global__ __launch_bounds__(256) void combine(const float* __restrict__ x,
                                               const float* __restrict__ part,
                                               float* __restrict__ out) {
    const int t = blockIdx.x * 256 + threadIdx.x;
    const int b = t / 1056;
    const int j = t - b * 1056;
    if (j < 1024) {
        out[t] = x[b * 1024 + j];
    } else {
        const int k = j - 1024;
        float s = 0.f;
#pragma unroll
        for (int i = 0; i < 16; ++i) s += part[i * (NBK * BATCH) + k * BATCH + b];
        out[t] = s;
    }
}

extern "C" void kernel_launch(void* const* d_in, const int* in_sizes, int n_in,
                              void* d_out, int out_size, void* d_ws, size_t ws_size,
                              hipStream_t stream) {
    const float* x = (const float*)d_in[0];
    const float* W = (const float*)d_in[1];
    float* out = (float*)d_out;

    unsigned short* xb = (unsigned short*)d_ws;                        // 2 MB
    unsigned short* wt = (unsigned short*)((char*)d_ws + 2*1024*1024); // 1 MB
    float* act2 = (float*)((char*)d_ws + 3 * 1024 * 1024);             // 2 MB
    float* part = (float*)((char*)d_ws + 5 * 1024 * 1024);             // 2 MB

    prep<<<640, 256, 0, stream>>>(x, W, xb, wt);
    gemm_direct<<<dim3(16, 32), 128, 0, stream>>>(xb, wt, act2);
    pairwise<<<dim3(16, 32), 256, 0, stream>>>(act2, part);
    combine<<<(BATCH * 1056 + 255) / 256, 256, 0, stream>>>(x, part, out);
}

// Round 4
// 106.921 us; speedup vs baseline: 1.3334x; 1.0241x over previous
//
#include <hip/hip_runtime.h>
#include <hip/hip_bf16.h>

#define BATCH 1024
#define INPUT_DIM 1024
#define NBK 32
#define KDIM 16

typedef __attribute__((ext_vector_type(8))) short short8;
typedef __attribute__((ext_vector_type(8))) unsigned short ushort8;
typedef __attribute__((ext_vector_type(4))) float f32x4;

static __device__ __forceinline__ unsigned short f2bf(float f) {
    union { float f; unsigned u; } v; v.f = f;
    unsigned r = v.u + 0x7fffu + ((v.u >> 16) & 1u);   // RNE
    return (unsigned short)(r >> 16);
}

// ---------------------------------------------------------------------------
// Kernel 0 (prep): blocks [0,512): x fp32 -> xb bf16 AND x -> out[b][0:1024].
//                  blocks [512,640): W[k][d][m] fp32 -> Wt[k][m][d] bf16.
// ---------------------------------------------------------------------------
__global__ __launch_bounds__(256) void prep(const float* __restrict__ x,
                                            const float* __restrict__ W,
                                            unsigned short* __restrict__ xb,
                                            unsigned short* __restrict__ wt,
                                            float* __restrict__ out) {
    const int blk = blockIdx.x;
    if (blk < 512) {
        const int i = (blk * 256 + threadIdx.x) * 8;
        float4 v0 = *(const float4*)(x + i);
        float4 v1 = *(const float4*)(x + i + 4);
        ushort8 o;
        o[0] = f2bf(v0.x); o[1] = f2bf(v0.y); o[2] = f2bf(v0.z); o[3] = f2bf(v0.w);
        o[4] = f2bf(v1.x); o[5] = f2bf(v1.y); o[6] = f2bf(v1.z); o[7] = f2bf(v1.w);
        *(ushort8*)(xb + i) = o;
        const int b = i >> 10;
        const int d = i & 1023;
        float* op = out + b * 1056 + d;
        *(float4*)(op)     = v0;
        *(float4*)(op + 4) = v1;
    } else {
        const int b2 = blk - 512;                  // 0..127
        const int k  = b2 >> 2;                    // 0..31
        const int d  = (b2 & 3) * 256 + threadIdx.x;
        const float* src = W + (k * INPUT_DIM + d) * KDIM;  // 16 contiguous floats
        float4 v0 = *(const float4*)(src + 0);
        float4 v1 = *(const float4*)(src + 4);
        float4 v2 = *(const float4*)(src + 8);
        float4 v3 = *(const float4*)(src + 12);
        unsigned short* dst = wt + k * (KDIM * INPUT_DIM) + d;  // stride 1024 per m
        dst[0 * INPUT_DIM]  = f2bf(v0.x); dst[1 * INPUT_DIM]  = f2bf(v0.y);
        dst[2 * INPUT_DIM]  = f2bf(v0.z); dst[3 * INPUT_DIM]  = f2bf(v0.w);
        dst[4 * INPUT_DIM]  = f2bf(v1.x); dst[5 * INPUT_DIM]  = f2bf(v1.y);
        dst[6 * INPUT_DIM]  = f2bf(v1.z); dst[7 * INPUT_DIM]  = f2bf(v1.w);
        dst[8 * INPUT_DIM]  = f2bf(v2.x); dst[9 * INPUT_DIM]  = f2bf(v2.y);
        dst[10 * INPUT_DIM] = f2bf(v2.z); dst[11 * INPUT_DIM] = f2bf(v2.w);
        dst[12 * INPUT_DIM] = f2bf(v3.x); dst[13 * INPUT_DIM] = f2bf(v3.y);
        dst[14 * INPUT_DIM] = f2bf(v3.z); dst[15 * INPUT_DIM] = f2bf(v3.w);
    }
}

// ---------------------------------------------------------------------------
// Kernel 1: act2[k][b][m] via bf16 MFMA 16x16x32, direct from L2, split-d.
// Block: 128 thr = 2 waves; both waves share (k, 32 b-rows); wave w reduces
// d in [w*512, w*512+512). Cross-wave add via 2 KB LDS, wave0 stores.
// Grid (32,32) = 1024 blocks = 2048 waves = 8 waves/CU = 2 waves/SIMD.
// ---------------------------------------------------------------------------
__global__ __launch_bounds__(128) void gemm_direct(const unsigned short* __restrict__ xb,
                                                   const unsigned short* __restrict__ wt,
                                                   float* __restrict__ act2) {
    __shared__ float red[2 * 64 * 4];   // 2 KB
    const int tid  = threadIdx.x;
    const int lane = tid & 63;
    const int w    = tid >> 6;                    // 0..1 (d-half)
    const int k    = blockIdx.y;
    const int b0   = blockIdx.x * 32;
    const int m16  = lane & 15;
    const int quad = lane >> 4;

    const unsigned short* a0p = xb + (b0 + m16) * INPUT_DIM + w * 512 + quad * 8;
    const unsigned short* a1p = a0p + 16 * INPUT_DIM;
    const unsigned short* bp  = wt + k * (KDIM * INPUT_DIM) + m16 * INPUT_DIM + w * 512 + quad * 8;

    f32x4 acc0 = {0.f, 0.f, 0.f, 0.f};
    f32x4 acc1 = {0.f, 0.f, 0.f, 0.f};

    short8 A0 = *(const short8*)a0p;
    short8 A1 = *(const short8*)a1p;
    short8 BV = *(const short8*)bp;

#pragma unroll 4
    for (int s = 0; s < 16; ++s) {
        const int sp = (s < 15) ? (s + 1) * 32 : 0;   // wrap: dead value, in-bounds
        short8 nA0 = *(const short8*)(a0p + sp);
        short8 nA1 = *(const short8*)(a1p + sp);
        short8 nBV = *(const short8*)(bp + sp);
        acc0 = __builtin_amdgcn_mfma_f32_16x16x32_bf16(A0, BV, acc0, 0, 0, 0);
        acc1 = __builtin_amdgcn_mfma_f32_16x16x32_bf16(A1, BV, acc1, 0, 0, 0);
        A0 = nA0; A1 = nA1; BV = nBV;
    }

    if (w == 1) {
        *(float4*)&red[lane * 4]       = make_float4(acc0[0], acc0[1], acc0[2], acc0[3]);
        *(float4*)&red[256 + lane * 4] = make_float4(acc1[0], acc1[1], acc1[2], acc1[3]);
    }
    __syncthreads();
    if (w == 0) {
        float4 o0 = *(const float4*)&red[lane * 4];
        float4 o1 = *(const float4*)&red[256 + lane * 4];
        const int row0 = b0 + quad * 4;               // C/D: col=lane&15, row=quad*4+r
        act2[(k * BATCH + row0 + 0) * KDIM + m16]  = acc0[0] + o0.x;
        act2[(k * BATCH + row0 + 1) * KDIM + m16]  = acc0[1] + o0.y;
        act2[(k * BATCH + row0 + 2) * KDIM + m16]  = acc0[2] + o0.z;
        act2[(k * BATCH + row0 + 3) * KDIM + m16]  = acc0[3] + o0.w;
        act2[(k * BATCH + row0 + 16) * KDIM + m16] = acc1[0] + o1.x;
        act2[(k * BATCH + row0 + 17) * KDIM + m16] = acc1[1] + o1.y;
        act2[(k * BATCH + row0 + 18) * KDIM + m16] = acc1[2] + o1.z;
        act2[(k * BATCH + row0 + 19) * KDIM + m16] = acc1[3] + o1.w;
    }
}

// ---------------------------------------------------------------------------
// Kernel 2: partial minibatch features, 4 b-rows per thread.
// grid = (c_chunk=32, k=32) = 1024 blocks x 256 thr = 4 blocks/CU
// = 16 waves/CU = 4 waves/SIMD. LDS: 32 c-rows (2 KB), broadcast reads.
// ---------------------------------------------------------------------------
__global__ __launch_bounds__(256) void pairwise(const float* __restrict__ act2,
                                                float* __restrict__ part) {
    __shared__ float cs[32 * KDIM];  // 2 KB
    const int tid = threadIdx.x;
    const int k   = blockIdx.y;
    const int c0  = blockIdx.x * 32;
    const float* base = act2 + k * (BATCH * KDIM);

    if (tid < 128) ((float4*)cs)[tid] = ((const float4*)(base + c0 * KDIM))[tid];

    float a[4][16];
#pragma unroll
    for (int r = 0; r < 4; ++r) {
#pragma unroll
        for (int i = 0; i < 4; ++i) {
            float4 v = *(const float4*)(base + (tid + r * 256) * KDIM + i * 4);
            a[r][i * 4 + 0] = v.x; a[r][i * 4 + 1] = v.y;
            a[r][i * 4 + 2] = v.z; a[r][i * 4 + 3] = v.w;
        }
    }
    __syncthreads();

    float f0 = 0.f, f1 = 0.f, f2 = 0.f, f3 = 0.f;
#pragma unroll 2
    for (int c = 0; c < 32; ++c) {
        const float4 r0 = *(const float4*)&cs[c * 16 + 0];
        const float4 r1 = *(const float4*)&cs[c * 16 + 4];
        const float4 r2 = *(const float4*)&cs[c * 16 + 8];
        const float4 r3 = *(const float4*)&cs[c * 16 + 12];
#define ROWSUM(rr)                                                           \
        (fabsf(a[rr][0]  - r0.x) + fabsf(a[rr][1]  - r0.y) +                 \
         fabsf(a[rr][2]  - r0.z) + fabsf(a[rr][3]  - r0.w) +                 \
         fabsf(a[rr][4]  - r1.x) + fabsf(a[rr][5]  - r1.y) +                 \
         fabsf(a[rr][6]  - r1.z) + fabsf(a[rr][7]  - r1.w) +                 \
         fabsf(a[rr][8]  - r2.x) + fabsf(a[rr][9]  - r2.y) +                 \
         fabsf(a[rr][10] - r2.z) + fabsf(a[rr][11] - r2.w) +                 \
         fabsf(a[rr][12] - r3.x) + fabsf(a[rr][13] - r3.y) +                 \
         fabsf(a[rr][14] - r3.z) + fabsf(a[rr][15] - r3.w))
        f0 += __expf(-ROWSUM(0));
        f1 += __expf(-ROWSUM(1));
        f2 += __expf(-ROWSUM(2));
        f3 += __expf(-ROWSUM(3));
#undef ROWSUM
    }
    float* p = part + blockIdx.x * (NBK * BATCH) + k * BATCH + tid;
    p[0]   = f0;
    p[256] = f1;
    p[512] = f2;
    p[768] = f3;
}

// ---------------------------------------------------------------------------
// Kernel 3: out[b][1024+k] = sum over 32 chunks of part[ch][k][b]
// (x-portion of out already written by prep). 32768 threads.
// ---------------------------------------------------------------------------
__global__ __launch_bounds__(256) void combine_feat(const float* __restrict__ part,
                                                    float* __restrict__ out) {
    const int t = blockIdx.x * 256 + threadIdx.x;   // k*1024 + b, t < 32768
    const int k = t >> 10;
    const int b = t & 1023;
    float s = 0.f;
#pragma unroll
    for (int i = 0; i < 32; ++i) s += part[i * (NBK * BATCH) + t];
    out[b * 1056 + 1024 + k] = s;
}

extern "C" void kernel_launch(void* const* d_in, const int* in_sizes, int n_in,
                              void* d_out, int out_size, void* d_ws, size_t ws_size,
                              hipStream_t stream) {
    const float* x = (const float*)d_in[0];
    const float* W = (const float*)d_in[1];
    float* out = (float*)d_out;

    unsigned short* xb = (unsigned short*)d_ws;                        // 2 MB
    unsigned short* wt = (unsigned short*)((char*)d_ws + 2*1024*1024); // 1 MB
    float* act2 = (float*)((char*)d_ws + 3 * 1024 * 1024);             // 2 MB
    float* part = (float*)((char*)d_ws + 5 * 1024 * 1024);             // 4 MB

    prep<<<640, 256, 0, stream>>>(x, W, xb, wt, out);
    gemm_direct<<<dim3(32, 32), 128, 0, stream>>>(xb, wt, act2);
    pairwise<<<dim3(32, 32), 256, 0, stream>>>(act2, part);
    combine_feat<<<128, 256, 0, stream>>>(part, out);
}